// Round 1
// baseline (1057.197 us; speedup 1.0000x reference)
//
#include <hip/hip_runtime.h>

#define S_LEN 2048
#define D_DIM 128
#define BM 128
#define BK 128
#define LDP 136  // padded LDS row stride (bf16 elements): 272B, 16B-aligned, 2-way banks

typedef __attribute__((ext_vector_type(8))) short bf16x8;  // 8 bf16 = 4 VGPRs
typedef __attribute__((ext_vector_type(4))) float f32x4;   // MFMA accumulator

__device__ __forceinline__ unsigned short f2bf(float x) {
    union { float f; unsigned u; } c; c.f = x;
    unsigned r = c.u + 0x7fffu + ((c.u >> 16) & 1u);  // RNE
    return (unsigned short)(r >> 16);
}
__device__ __forceinline__ unsigned pack2(float a, float b) {
    return (unsigned)f2bf(a) | ((unsigned)f2bf(b) << 16);
}

// One block: 128 Q-rows of one (b,h). Loop over t in chunks of 128:
//   S^T = K·Q^T (so mask loads are dwordx4 and P writes are b64),
//   P = S ∘ mask -> bf16 LDS [s][t],
//   O += P·V with V staged transposed [d][t] for b128 B-operand reads.
__global__ __launch_bounds__(256, 1)
void fused_qkmv(const float* __restrict__ q, const float* __restrict__ k,
                const float* __restrict__ v, const float* __restrict__ mask,
                float* __restrict__ out) {
    __shared__ unsigned short Qs[BM * LDP];     // Q[s][d] bf16
    __shared__ unsigned short Ks[BK * LDP];     // K[t][d] bf16
    __shared__ unsigned short Vt[D_DIM * LDP];  // V^T[d][t] bf16
    __shared__ unsigned short Ps[BM * LDP];     // P[s][t] bf16

    const int tid  = threadIdx.x;
    const int lane = tid & 63;
    const int wave = tid >> 6;
    const int wt   = wave >> 1;  // t-quadrant (S^T gemm) / s-quadrant (O)
    const int wc   = wave & 1;   // s-quadrant (S^T gemm) / d-quadrant (O)
    const int l15  = lane & 15;
    const int quad = lane >> 4;

    const int bh    = blockIdx.x >> 4;
    const int qtile = blockIdx.x & 15;
    const int s0    = qtile * BM;

    const float* qp = q + (size_t)bh * S_LEN * D_DIM;
    const float* kp = k + (size_t)bh * S_LEN * D_DIM;
    const float* vp = v + (size_t)bh * S_LEN * D_DIM;
    const float* mp = mask + (size_t)bh * S_LEN * S_LEN;
    float*       op = out + (size_t)bh * S_LEN * D_DIM;

    // ---- stage Q tile once: rows s0..s0+127, fp32 -> bf16 ----
    {
        const int r = tid >> 5, d = (tid & 31) * 4;
#pragma unroll
        for (int sw = 0; sw < 16; ++sw) {
            const int row = sw * 8 + r;
            float4 f = *(const float4*)(qp + (size_t)(s0 + row) * D_DIM + d);
            uint2 w; w.x = pack2(f.x, f.y); w.y = pack2(f.z, f.w);
            *(uint2*)&Qs[row * LDP + d] = w;
        }
    }

    f32x4 acc_o[4][4];
#pragma unroll
    for (int i = 0; i < 4; ++i)
#pragma unroll
        for (int j = 0; j < 4; ++j) acc_o[i][j] = (f32x4){0.f, 0.f, 0.f, 0.f};

    for (int it = 0; it < S_LEN / BK; ++it) {
        const int t0 = it * BK;

        // ---- issue mask loads early (consumed after S-gemm: big latency window) ----
        float4 mreg[4][4];
        {
            const float* mb = mp + (size_t)(s0 + wc * 64 + l15) * S_LEN
                            + t0 + wt * 64 + quad * 4;
#pragma unroll
            for (int ti = 0; ti < 4; ++ti)
#pragma unroll
                for (int sj = 0; sj < 4; ++sj)
                    mreg[ti][sj] = *(const float4*)(mb + (size_t)sj * 16 * S_LEN + ti * 16);
        }

        // ---- stage K tile [t][d] ----
        {
            const int r = tid >> 5, d = (tid & 31) * 4;
#pragma unroll
            for (int sw = 0; sw < 16; ++sw) {
                const int row = sw * 8 + r;
                float4 f = *(const float4*)(kp + (size_t)(t0 + row) * D_DIM + d);
                uint2 w; w.x = pack2(f.x, f.y); w.y = pack2(f.z, f.w);
                *(uint2*)&Ks[row * LDP + d] = w;
            }
        }
        // ---- stage V transposed: Vt[d][t] (4x4 micro-tiles; b64 LDS writes, conflict-free) ----
        {
            const int t = (tid & 31) * 4, db = (tid >> 5) * 4;
#pragma unroll
            for (int mi = 0; mi < 4; ++mi) {
                const int d = db + 32 * mi;
                float4 r0 = *(const float4*)(vp + (size_t)(t0 + t + 0) * D_DIM + d);
                float4 r1 = *(const float4*)(vp + (size_t)(t0 + t + 1) * D_DIM + d);
                float4 r2 = *(const float4*)(vp + (size_t)(t0 + t + 2) * D_DIM + d);
                float4 r3 = *(const float4*)(vp + (size_t)(t0 + t + 3) * D_DIM + d);
                uint2 w;
                w.x = pack2(r0.x, r1.x); w.y = pack2(r2.x, r3.x);
                *(uint2*)&Vt[(d + 0) * LDP + t] = w;
                w.x = pack2(r0.y, r1.y); w.y = pack2(r2.y, r3.y);
                *(uint2*)&Vt[(d + 1) * LDP + t] = w;
                w.x = pack2(r0.z, r1.z); w.y = pack2(r2.z, r3.z);
                *(uint2*)&Vt[(d + 2) * LDP + t] = w;
                w.x = pack2(r0.w, r1.w); w.y = pack2(r2.w, r3.w);
                *(uint2*)&Vt[(d + 3) * LDP + t] = w;
            }
        }

        f32x4 acc_s[4][4];
#pragma unroll
        for (int i = 0; i < 4; ++i)
#pragma unroll
            for (int j = 0; j < 4; ++j) acc_s[i][j] = (f32x4){0.f, 0.f, 0.f, 0.f};

        __syncthreads();  // staging visible

        // ---- S^T = K·Q^T : A=K[t][d], B=Q^T (read Q[s][d]); both b128 LDS reads ----
#pragma unroll
        for (int kc = 0; kc < 4; ++kc) {
            const int koff = kc * 32 + quad * 8;
            bf16x8 af[4], bq[4];
#pragma unroll
            for (int ti = 0; ti < 4; ++ti)
                af[ti] = *(const bf16x8*)&Ks[(wt * 64 + ti * 16 + l15) * LDP + koff];
#pragma unroll
            for (int sj = 0; sj < 4; ++sj)
                bq[sj] = *(const bf16x8*)&Qs[(wc * 64 + sj * 16 + l15) * LDP + koff];
#pragma unroll
            for (int ti = 0; ti < 4; ++ti)
#pragma unroll
                for (int sj = 0; sj < 4; ++sj)
                    acc_s[ti][sj] = __builtin_amdgcn_mfma_f32_16x16x32_bf16(
                        af[ti], bq[sj], acc_s[ti][sj], 0, 0, 0);
        }

        // ---- P = S ∘ mask -> bf16 -> Ps[s][t]; lane's 4 regs are 4 consecutive t => b64 ----
#pragma unroll
        for (int ti = 0; ti < 4; ++ti)
#pragma unroll
            for (int sj = 0; sj < 4; ++sj) {
                f32x4 sv = acc_s[ti][sj];
                float4 m = mreg[ti][sj];
                uint2 w;
                w.x = pack2(sv[0] * m.x, sv[1] * m.y);
                w.y = pack2(sv[2] * m.z, sv[3] * m.w);
                *(uint2*)&Ps[(wc * 64 + sj * 16 + l15) * LDP + wt * 64 + ti * 16 + quad * 4] = w;
            }

        __syncthreads();  // P visible

        // ---- O += P·V : A=P[s][t], B=V^T[d][t]; both b128 LDS reads ----
#pragma unroll
        for (int kc = 0; kc < 4; ++kc) {
            const int koff = kc * 32 + quad * 8;
            bf16x8 ap[4], bv[4];
#pragma unroll
            for (int si = 0; si < 4; ++si)
                ap[si] = *(const bf16x8*)&Ps[(wt * 64 + si * 16 + l15) * LDP + koff];
#pragma unroll
            for (int dj = 0; dj < 4; ++dj)
                bv[dj] = *(const bf16x8*)&Vt[(wc * 64 + dj * 16 + l15) * LDP + koff];
#pragma unroll
            for (int si = 0; si < 4; ++si)
#pragma unroll
                for (int dj = 0; dj < 4; ++dj)
                    acc_o[si][dj] = __builtin_amdgcn_mfma_f32_16x16x32_bf16(
                        ap[si], bv[dj], acc_o[si][dj], 0, 0, 0);
        }

        __syncthreads();  // protect Ks/Vt/Ps before next iter's staging
    }

    // ---- epilogue: O rows = wt*64.., cols = wc*64.. ; C-layout row=quad*4+reg, col=l15 ----
#pragma unroll
    for (int si = 0; si < 4; ++si)
#pragma unroll
        for (int dj = 0; dj < 4; ++dj) {
            const int d = wc * 64 + dj * 16 + l15;
#pragma unroll
            for (int r2 = 0; r2 < 4; ++r2) {
                const int srow = s0 + wt * 64 + si * 16 + quad * 4 + r2;
                op[(size_t)srow * D_DIM + d] = acc_o[si][dj][r2];
            }
        }
}

extern "C" void kernel_launch(void* const* d_in, const int* in_sizes, int n_in,
                              void* d_out, int out_size, void* d_ws, size_t ws_size,
                              hipStream_t stream) {
    const float* q = (const float*)d_in[0];
    const float* k = (const float*)d_in[1];
    const float* v = (const float*)d_in[2];
    const float* m = (const float*)d_in[3];
    float* out = (float*)d_out;
    // 2*16 heads * 16 q-tiles = 512 blocks, 256 threads (4 waves)
    fused_qkmv<<<dim3(512), dim3(256), 0, stream>>>(q, k, v, m, out);
}

// Round 2
// 794.510 us; speedup vs baseline: 1.3306x; 1.3306x over previous
//
#include <hip/hip_runtime.h>

#define S_LEN 2048
#define D_DIM 128
#define BM 128
#define BK 64
#define NIT (S_LEN / BK)
#define LQ 136   // Qs/Ks row stride (bf16 elems): 272B rows, 16B-aligned
#define LV 72    // Vt row stride (bf16 elems): 144B rows, 16B-aligned

typedef __attribute__((ext_vector_type(8))) short bf16x8;  // 8 bf16 (4 VGPRs)
typedef __attribute__((ext_vector_type(4))) float f32x4;   // MFMA accumulator
typedef __attribute__((ext_vector_type(4))) int i32x4;

__device__ __forceinline__ unsigned short f2bf(float x) {
    union { float f; unsigned u; } c; c.f = x;
    unsigned r = c.u + 0x7fffu + ((c.u >> 16) & 1u);  // RNE
    return (unsigned short)(r >> 16);
}
__device__ __forceinline__ unsigned pack2(float a, float b) {
    return (unsigned)f2bf(a) | ((unsigned)f2bf(b) << 16);
}

// One block: 128 Q-rows of one (b,h); 32 iters over t-chunks of 64.
//   S^T = K·Q^T (mask loads dwordx4, C-layout col = s = lane&15)
//   P = S∘mask -> bf16, redistributed to O-gemm A-layout via ds_bpermute
//     (no Ps LDS tile, no extra barriers: only the quad dim permutes)
//   O += P·V with V staged transposed [d][t].
// LDS = 70.6 KB -> 2 blocks/CU (8 waves/CU); 512 blocks all co-resident.
__global__ __launch_bounds__(256, 2)
void fused_qkmv(const float* __restrict__ q, const float* __restrict__ k,
                const float* __restrict__ v, const float* __restrict__ mask,
                float* __restrict__ out) {
    __shared__ unsigned short Qs[BM * LQ];     // Q[s][d] bf16  (34816 B)
    __shared__ unsigned short Ks[BK * LQ];     // K[t][d] bf16  (17408 B)
    __shared__ unsigned short Vt[D_DIM * LV];  // V^T[d][t] bf16 (18432 B)

    const int tid  = threadIdx.x;
    const int lane = tid & 63;
    const int w    = tid >> 6;   // wave 0..3: s-range 32w..32w+32
    const int l15  = lane & 15;
    const int qd   = lane >> 4;  // quad

    const int bh = blockIdx.x >> 4;
    const int s0 = (blockIdx.x & 15) * BM;

    const float* qp = q + (size_t)bh * S_LEN * D_DIM;
    const float* kp = k + (size_t)bh * S_LEN * D_DIM;
    const float* vp = v + (size_t)bh * S_LEN * D_DIM;
    const float* mp = mask + (size_t)bh * S_LEN * S_LEN;
    float*       op = out + (size_t)bh * S_LEN * D_DIM;

    // ---- stage Q tile once (fp32 -> bf16) ----
    {
        const int r = tid >> 5, d = (tid & 31) * 4;
#pragma unroll
        for (int sw = 0; sw < 16; ++sw) {
            const int row = sw * 8 + r;
            float4 f = *(const float4*)(qp + (size_t)(s0 + row) * D_DIM + d);
            uint2 wv; wv.x = pack2(f.x, f.y); wv.y = pack2(f.z, f.w);
            *(uint2*)&Qs[row * LQ + d] = wv;
        }
    }

    f32x4 acc_o[2][8];
#pragma unroll
    for (int i = 0; i < 2; ++i)
#pragma unroll
        for (int j = 0; j < 8; ++j) acc_o[i][j] = (f32x4){0.f, 0.f, 0.f, 0.f};

    // bpermute source-lane byte addresses (src quad = 2*(qd&1) [+1], same l15)
    const int a0 = ((2 * (qd & 1)) * 16 + l15) * 4;
    const int a1 = a0 + 64;
    const bool hi = (qd >= 2);  // dest quads 2,3 pull from the odd ti tile

    for (int it = 0; it < NIT; ++it) {
        const int t0 = it * BK;

        // ---- mask loads (consumed after S-gemm: long latency window) ----
        float4 mreg[4][2];  // [ti][sj]: row s = s0+32w+16sj+l15, col t0+16ti+4qd..+4
        {
            const float* mb = mp + (size_t)(s0 + 32 * w + l15) * S_LEN + t0 + 4 * qd;
#pragma unroll
            for (int ti = 0; ti < 4; ++ti)
#pragma unroll
                for (int sj = 0; sj < 2; ++sj)
                    mreg[ti][sj] = *(const float4*)(mb + (size_t)sj * 16 * S_LEN + ti * 16);
        }

        // ---- stage K tile [t][d]: coalesced 64B segments ----
        {
            const int tk = tid >> 2, dk = (tid & 3) * 4;
            float4 f[8];
#pragma unroll
            for (int i = 0; i < 8; ++i)
                f[i] = *(const float4*)(kp + (size_t)(t0 + tk) * D_DIM + dk + 16 * i);
#pragma unroll
            for (int i = 0; i < 8; ++i) {
                uint2 wv; wv.x = pack2(f[i].x, f[i].y); wv.y = pack2(f[i].z, f[i].w);
                *(uint2*)&Ks[tk * LQ + dk + 16 * i] = wv;
            }
        }
        // ---- stage V transposed: Vt[d][t] ----
        {
            const int tg = (tid & 15) * 4, dg = (tid >> 4) * 8;
            float4 ra[4], rb[4];
#pragma unroll
            for (int r = 0; r < 4; ++r) {
                ra[r] = *(const float4*)(vp + (size_t)(t0 + tg + r) * D_DIM + dg);
                rb[r] = *(const float4*)(vp + (size_t)(t0 + tg + r) * D_DIM + dg + 4);
            }
#pragma unroll
            for (int i = 0; i < 4; ++i) {
                uint2 wv;
                wv.x = pack2(((const float*)&ra[0])[i], ((const float*)&ra[1])[i]);
                wv.y = pack2(((const float*)&ra[2])[i], ((const float*)&ra[3])[i]);
                *(uint2*)&Vt[(dg + i) * LV + tg] = wv;
                uint2 wv2;
                wv2.x = pack2(((const float*)&rb[0])[i], ((const float*)&rb[1])[i]);
                wv2.y = pack2(((const float*)&rb[2])[i], ((const float*)&rb[3])[i]);
                *(uint2*)&Vt[(dg + 4 + i) * LV + tg] = wv2;
            }
        }

        f32x4 acc_s[4][2];
#pragma unroll
        for (int i = 0; i < 4; ++i)
#pragma unroll
            for (int j = 0; j < 2; ++j) acc_s[i][j] = (f32x4){0.f, 0.f, 0.f, 0.f};

        __syncthreads();  // staging visible

        // ---- S^T = K·Q^T : A=K[t][d], B=Q^T; tiles ti(t) x sj(s) ----
#pragma unroll
        for (int kc = 0; kc < 4; ++kc) {
            const int ko = kc * 32 + qd * 8;
            bf16x8 af[4], bq[2];
#pragma unroll
            for (int ti = 0; ti < 4; ++ti)
                af[ti] = *(const bf16x8*)&Ks[(16 * ti + l15) * LQ + ko];
#pragma unroll
            for (int sj = 0; sj < 2; ++sj)
                bq[sj] = *(const bf16x8*)&Qs[(32 * w + 16 * sj + l15) * LQ + ko];
#pragma unroll
            for (int ti = 0; ti < 4; ++ti)
#pragma unroll
                for (int sj = 0; sj < 2; ++sj)
                    acc_s[ti][sj] = __builtin_amdgcn_mfma_f32_16x16x32_bf16(
                        af[ti], bq[sj], acc_s[ti][sj], 0, 0, 0);
        }

        // ---- P = S^T ∘ mask -> packed bf16 (per source lane: t = 16ti+4qd+{0..3}) ----
        int pu[4][2][2];
#pragma unroll
        for (int ti = 0; ti < 4; ++ti)
#pragma unroll
            for (int sj = 0; sj < 2; ++sj) {
                f32x4 sv = acc_s[ti][sj];
                float4 m = mreg[ti][sj];
                pu[ti][sj][0] = (int)pack2(sv[0] * m.x, sv[1] * m.y);
                pu[ti][sj][1] = (int)pack2(sv[2] * m.z, sv[3] * m.w);
            }

        // ---- quad-exchange to O-gemm A-layout + O += P·V ----
#pragma unroll
        for (int kc2 = 0; kc2 < 2; ++kc2) {
            bf16x8 ap[2];
#pragma unroll
            for (int sj = 0; sj < 2; ++sj) {
                const int tA = 2 * kc2, tB = 2 * kc2 + 1;
                int w0a = __builtin_amdgcn_ds_bpermute(a0, pu[tA][sj][0]);
                int w0b = __builtin_amdgcn_ds_bpermute(a0, pu[tB][sj][0]);
                int w1a = __builtin_amdgcn_ds_bpermute(a0, pu[tA][sj][1]);
                int w1b = __builtin_amdgcn_ds_bpermute(a0, pu[tB][sj][1]);
                int w2a = __builtin_amdgcn_ds_bpermute(a1, pu[tA][sj][0]);
                int w2b = __builtin_amdgcn_ds_bpermute(a1, pu[tB][sj][0]);
                int w3a = __builtin_amdgcn_ds_bpermute(a1, pu[tA][sj][1]);
                int w3b = __builtin_amdgcn_ds_bpermute(a1, pu[tB][sj][1]);
                union { i32x4 i; bf16x8 b; } u;
                u.i = (i32x4){hi ? w0b : w0a, hi ? w1b : w1a,
                              hi ? w2b : w2a, hi ? w3b : w3a};
                ap[sj] = u.b;
            }
            const int ko = kc2 * 32 + qd * 8;
#pragma unroll
            for (int dj = 0; dj < 8; ++dj) {
                bf16x8 bv = *(const bf16x8*)&Vt[(16 * dj + l15) * LV + ko];
#pragma unroll
                for (int si = 0; si < 2; ++si)
                    acc_o[si][dj] = __builtin_amdgcn_mfma_f32_16x16x32_bf16(
                        ap[si], bv, acc_o[si][dj], 0, 0, 0);
            }
        }

        __syncthreads();  // all LDS reads done; next iter may overwrite Ks/Vt
    }

    // ---- epilogue: O[s][d], C-layout row=4qd+r, col=l15 ----
#pragma unroll
    for (int si = 0; si < 2; ++si)
#pragma unroll
        for (int dj = 0; dj < 8; ++dj) {
#pragma unroll
            for (int r = 0; r < 4; ++r) {
                const int srow = s0 + 32 * w + 16 * si + 4 * qd + r;
                op[(size_t)srow * D_DIM + 16 * dj + l15] = acc_o[si][dj][r];
            }
        }
}

extern "C" void kernel_launch(void* const* d_in, const int* in_sizes, int n_in,
                              void* d_out, int out_size, void* d_ws, size_t ws_size,
                              hipStream_t stream) {
    const float* q = (const float*)d_in[0];
    const float* k = (const float*)d_in[1];
    const float* v = (const float*)d_in[2];
    const float* m = (const float*)d_in[3];
    float* out = (float*)d_out;
    // 32 heads * 16 q-tiles = 512 blocks; 2 blocks/CU co-resident
    fused_qkmv<<<dim3(512), dim3(256), 0, stream>>>(q, k, v, m, out);
}